// Round 8
// baseline (183.584 us; speedup 1.0000x reference)
//
#include <hip/hip_runtime.h>
#include <math.h>

#define NN 512   // set size / rows of feat_x
#define IN 512   // INPUT_DIM
#define HD 256   // HIDDEN_DIM
#define RD 256   // REP_DIM
#define SH 128   // SCORE_HIDDEN

// Branchless erf-GELU, Abramowitz-Stegun 7.1.26 (|erf err| <= 1.5e-7).
__device__ __forceinline__ float gelu_fast(float x){
    const float z  = x * 0.70710678118654752f;
    const float az = fabsf(z);
    const float t  = __builtin_amdgcn_rcpf(fmaf(0.3275911f, az, 1.0f));
    float p = fmaf(1.061405429f, t, -1.453152027f);
    p = fmaf(p, t, 1.421413741f);
    p = fmaf(p, t, -0.284496736f);
    p = fmaf(p, t, 0.254829592f);
    p = p * t;
    const float e = __builtin_amdgcn_exp2f(z * z * -1.4426950408889634f);
    const float E = p * e;                        // erfc(|z|)
    const float one_plus_erf = (x >= 0.0f) ? (2.0f - E) : E;
    return 0.5f * x * one_plus_erf;
}

// u*(1+erf(u/sqrt2)) -- the 0.5 is folded into the caller's weight.
__device__ __forceinline__ float gelu2(float u){
    const float az = fabsf(u);
    const float tt = __builtin_amdgcn_rcpf(fmaf(0.23166045f, az, 1.0f));
    float p = fmaf(1.061405429f, tt, -1.453152027f);
    p = fmaf(p, tt, 1.421413741f);
    p = fmaf(p, tt, -0.284496736f);
    p = fmaf(p, tt, 0.254829592f);
    p = p * tt;
    const float e2 = __builtin_amdgcn_exp2f(u * u * -0.72134752044448170f);
    const float Eq = p * e2;                      // erfc(|u|/sqrt2)
    const float ope = (u >= 0.0f) ? (2.0f - Eq) : Eq;
    return u * ope;
}

// K_REP: fused g-MLP + score-net projections. 768 blocks (3 mats x 256
// 2-row groups) x 256 thr = exactly 3 blocks/CU. Outputs: r row-major
// (for k_fin), rT/BT column-major (for k_sd's coalesced per-m sweeps),
// A_x row-major (for k_sd's per-n staging).
__global__ __launch_bounds__(256) void k_rep(
    const float* __restrict__ fx, const float* __restrict__ fp, const float* __restrict__ fn,
    const float* __restrict__ w1, const float* __restrict__ b1,
    const float* __restrict__ w2, const float* __restrict__ b2,
    const float* __restrict__ s_w1,
    float* __restrict__ r_x, float* __restrict__ r_p, float* __restrict__ r_n,
    float* __restrict__ rT_p, float* __restrict__ rT_n,
    float* __restrict__ A_x, float* __restrict__ BT_p, float* __restrict__ BT_n)
{
    __shared__ float xs[2][IN];        // 4 KB
    __shared__ float ps[4][2][HD];     // 8 KB
    __shared__ float hs[2][HD];        // 2 KB
    __shared__ float rloc[2][RD];      // 2 KB
    __shared__ float psf[8][2][SH];    // 8 KB
    __shared__ float ab2[2][SH];       // 1 KB
    const int t = threadIdx.x;
    const int mat = blockIdx.x >> 8;
    const int row0 = (blockIdx.x & 255) << 1;
    const float* src = (mat==0) ? fx : (mat==1) ? fp : fn;

    {   // stage 2 feat rows: 256 float4s
        const int j = t >> 7, q = (t & 127) << 2;
        *(float4*)&xs[j][q] = *(const float4*)&src[(row0+j)*IN + q];
    }
    __syncthreads();

    const int cg = t & 63, s = t >> 6;     // 64 colgroups x 4 K-slices
    const int c0 = cg << 2;

    {   // GEMM1: K=512 in 4 slices of 128
        float4 a0 = make_float4(0.f,0.f,0.f,0.f), a1 = a0;
        const float* wp = w1 + (s*128)*HD + c0;
        #pragma unroll 8
        for (int ii=0; ii<128; ii++){
            float4 w = *(const float4*)wp; wp += HD;
            const int i = s*128 + ii;
            const float x0 = xs[0][i], x1 = xs[1][i];
            a0.x = fmaf(x0, w.x, a0.x); a0.y = fmaf(x0, w.y, a0.y);
            a0.z = fmaf(x0, w.z, a0.z); a0.w = fmaf(x0, w.w, a0.w);
            a1.x = fmaf(x1, w.x, a1.x); a1.y = fmaf(x1, w.y, a1.y);
            a1.z = fmaf(x1, w.z, a1.z); a1.w = fmaf(x1, w.w, a1.w);
        }
        *(float4*)&ps[s][0][c0] = a0;
        *(float4*)&ps[s][1][c0] = a1;
    }
    __syncthreads();

    #pragma unroll
    for (int rep=0; rep<2; rep++){   // reduce + bias + GELU -> hs
        const int idx = rep*256 + t;
        const int j = idx >> 8, c = idx & 255;
        const float v = b1[c] + ps[0][j][c] + ps[1][j][c] + ps[2][j][c] + ps[3][j][c];
        hs[j][c] = gelu_fast(v);
    }
    __syncthreads();

    {   // GEMM2: K=256 in 4 slices of 64
        float4 a0 = make_float4(0.f,0.f,0.f,0.f), a1 = a0;
        const float* wp = w2 + (s*64)*RD + c0;
        #pragma unroll 8
        for (int ii=0; ii<64; ii++){
            float4 w = *(const float4*)wp; wp += RD;
            const int i = s*64 + ii;
            const float x0 = hs[0][i], x1 = hs[1][i];
            a0.x = fmaf(x0, w.x, a0.x); a0.y = fmaf(x0, w.y, a0.y);
            a0.z = fmaf(x0, w.z, a0.z); a0.w = fmaf(x0, w.w, a0.w);
            a1.x = fmaf(x1, w.x, a1.x); a1.y = fmaf(x1, w.y, a1.y);
            a1.z = fmaf(x1, w.z, a1.z); a1.w = fmaf(x1, w.w, a1.w);
        }
        *(float4*)&ps[s][0][c0] = a0;
        *(float4*)&ps[s][1][c0] = a1;
    }
    __syncthreads();

    float* rout = (mat==0) ? r_x : (mat==1) ? r_p : r_n;
    #pragma unroll
    for (int rep=0; rep<2; rep++){   // reduce + bias -> rloc + global r
        const int idx = rep*256 + t;
        const int j = idx >> 8, c = idx & 255;
        const float v = b2[c] + ps[0][j][c] + ps[1][j][c] + ps[2][j][c] + ps[3][j][c];
        rloc[j][c] = v;
        rout[(row0+j)*RD + c] = v;
    }
    __syncthreads();

    if (mat){   // transposed rep copy: column-major rT[r][m]
        float* rT = (mat==1) ? rT_p : rT_n;
        rT[t*NN + row0]     = rloc[0][t];
        rT[t*NN + row0 + 1] = rloc[1][t];
    }

    {   // score-net projection: 128 cols, K=256 in 8 slices of 32
        const int cg2 = t & 31, s2 = t >> 5;
        const int cc0 = cg2 << 2;
        const float sgn = (mat==0) ? -1.0f : 1.0f;
        const int base1 = (mat==0) ? 0 : 256;
        const float* p1 = s_w1 + (base1 + s2*32)*SH + cc0;
        const float* p3 = s_w1 + (512   + s2*32)*SH + cc0;
        float4 a0 = make_float4(0.f,0.f,0.f,0.f), a1 = a0;
        #pragma unroll 8
        for (int ii=0; ii<32; ii++){
            float4 wa = *(const float4*)p1; p1 += SH;
            float4 wd = *(const float4*)p3; p3 += SH;
            float4 w;
            w.x = fmaf(sgn, wd.x, wa.x);
            w.y = fmaf(sgn, wd.y, wa.y);
            w.z = fmaf(sgn, wd.z, wa.z);
            w.w = fmaf(sgn, wd.w, wa.w);
            const int i = s2*32 + ii;
            const float x0 = rloc[0][i], x1 = rloc[1][i];
            a0.x = fmaf(x0, w.x, a0.x); a0.y = fmaf(x0, w.y, a0.y);
            a0.z = fmaf(x0, w.z, a0.z); a0.w = fmaf(x0, w.w, a0.w);
            a1.x = fmaf(x1, w.x, a1.x); a1.y = fmaf(x1, w.y, a1.y);
            a1.z = fmaf(x1, w.z, a1.z); a1.w = fmaf(x1, w.w, a1.w);
        }
        *(float4*)&psf[s2][0][cc0] = a0;
        *(float4*)&psf[s2][1][cc0] = a1;
    }
    __syncthreads();

    {   // reduce 8 slices: 2 rows x 128 cols
        const int j = t >> 7, c = t & 127;
        float v = 0.f;
        #pragma unroll
        for (int ss=0; ss<8; ss++) v += psf[ss][j][c];
        if (mat==0) A_x[(row0+j)*SH + c] = v;   // row-major [n][k]
        else        ab2[j][c] = v;
    }
    __syncthreads();
    if (mat && t < 128){   // column-major BT[k][m]
        float* BT = (mat==1) ? BT_p : BT_n;
        BT[t*NN + row0]     = ab2[0][t];
        BT[t*NN + row0 + 1] = ab2[1][t];
    }
}

// K_SD: 2048 blocks (set x 256 2-row ntiles x 4 128-m mtiles) x 256 thr
// = 8 blocks/CU = 32 waves/CU. Wave-level k-split: waves 0,1 take the low
// r/k half for m 0..63 / 64..127; waves 2,3 the high half. Lanes sweep
// consecutive m against column-major yT/BT -> all loads coalesced; halves
// combine via stride-8B LDS (conflict-free). 2 rows/thread amortization.
__global__ __launch_bounds__(256) void k_sd(
    const float* __restrict__ r_x, const float* __restrict__ rT_p, const float* __restrict__ rT_n,
    const float* __restrict__ A_x, const float* __restrict__ BT_p, const float* __restrict__ BT_n,
    const float* __restrict__ s_w1, const float* __restrict__ s_b1,
    const float* __restrict__ s_w2,
    float* __restrict__ E_p, float* __restrict__ E_n, float* __restrict__ Spart)
{
    __shared__ float2 xs2[RD];        // 2 KB: {x0,x1}[r]
    __shared__ float4 cmb[SH];        // 2 KB: {A0+b1, A1+b1, wn, 0.5*w2}
    __shared__ float4 pd4[2][128];    // 4 KB: per-(half,m) partials
    __shared__ float nx[2];
    __shared__ float ssum[2][2];      // [m-half][row]
    const int t = threadIdx.x;
    const int set = blockIdx.x >> 10;
    const int rem = blockIdx.x & 1023;
    const int n0 = (rem >> 2) << 1;
    const int mt = rem & 3;
    const int mbase = mt << 7;
    const int tm = t & 127, kh = t >> 7;   // kh uniform per wave
    const int m = mbase + tm;
    const float* yT = set ? rT_n : rT_p;
    const float* BT = set ? BT_n : BT_p;
    float* E = set ? E_n : E_p;

    xs2[t] = make_float2(r_x[n0*RD + t], r_x[(n0+1)*RD + t]);
    if (t < SH){
        const float b1v = s_b1[t];
        cmb[t] = make_float4(A_x[n0*SH + t] + b1v,
                             A_x[(n0+1)*SH + t] + b1v,
                             s_w1[768*SH + t],
                             0.5f * s_w2[t]);
    }
    __syncthreads();

    // x-row norms (waves 0,1 -> rows 0,1); consumed after the pd barrier
    if (t < 128){
        const int w = t >> 6, l = t & 63;
        float v = 0.f;
        #pragma unroll
        for (int q=0;q<4;q++){
            const float2 e = xs2[l + 64*q];
            const float ev = w ? e.y : e.x;
            v = fmaf(ev, ev, v);
        }
        #pragma unroll
        for (int off=32; off>=1; off>>=1) v += __shfl_xor(v, off);
        if (l==0) nx[w] = v;
    }

    // phase 1: dots + ||y||^2 over this wave's r-half (coalesced scalar loads)
    float d0=0.f, d1=0.f, ny=0.f;
    {
        const float* yp = yT + (kh << 7)*NN + m;
        #pragma unroll 8
        for (int rr=0; rr<128; rr++){
            const float y = yp[rr*NN];
            const float2 xv = xs2[(kh << 7) + rr];
            d0 = fmaf(xv.x, y, d0);
            d1 = fmaf(xv.y, y, d1);
            ny = fmaf(y, y, ny);
        }
    }
    pd4[kh][tm] = make_float4(d0, d1, ny, 0.f);
    __syncthreads();
    {
        const float4 o = pd4[1-kh][tm];
        d0 += o.x; d1 += o.y; ny += o.z;
    }
    const float dn0 = sqrtf(fmaxf(fmaf(-2.f, d0, nx[0] + ny), 0.f));
    const float dn1 = sqrtf(fmaxf(fmaf(-2.f, d1, nx[1] + ny), 0.f));

    // phase 2: logits over this wave's k-half (coalesced scalar BT loads)
    float acc0 = 0.f, acc1 = 0.f;
    {
        const float* bp = BT + (kh << 6)*NN + m;
        #pragma unroll 4
        for (int kk=0; kk<64; kk++){
            const float b = bp[kk*NN];
            const float4 c = cmb[(kh << 6) + kk];
            const float u0 = fmaf(dn0, c.z, c.x + b);
            const float u1 = fmaf(dn1, c.z, c.y + b);
            acc0 = fmaf(c.w, gelu2(u0), acc0);
            acc1 = fmaf(c.w, gelu2(u1), acc1);
        }
    }
    __syncthreads();                       // partner finished reading phase-1 pd4
    pd4[kh][tm] = make_float4(acc0, acc1, 0.f, 0.f);
    __syncthreads();
    if (kh == 0){
        const float4 o = pd4[1][tm];
        // s_b2 omitted (softmax shift-invariant); no max pass (logits O(1))
        const float ev0 = __builtin_amdgcn_exp2f((acc0 + o.x) * 1.4426950408889634f);
        const float ev1 = __builtin_amdgcn_exp2f((acc1 + o.y) * 1.4426950408889634f);
        E[n0*NN + m]     = ev0;
        E[(n0+1)*NN + m] = ev1;
        float v0 = ev0, v1 = ev1;
        #pragma unroll
        for (int off=32; off>=1; off>>=1){ v0 += __shfl_xor(v0, off); v1 += __shfl_xor(v1, off); }
        if ((t & 63) == 0){
            ssum[tm >> 6][0] = v0;
            ssum[tm >> 6][1] = v1;
        }
    }
    __syncthreads();
    if (t < 2)
        Spart[(set*4 + mt)*NN + n0 + t] = ssum[0][t] + ssum[1][t];
}

// K_FIN: merged dv + out-projection (dv is block-local, no global sync).
// 256 blocks x 512 thr (8 waves, 2/SIMD). psum buffer eliminated.
__global__ __launch_bounds__(512) void k_fin(
    const float* __restrict__ E_p, const float* __restrict__ E_n,
    const float* __restrict__ Spart,
    const float* __restrict__ r_p, const float* __restrict__ r_n,
    const float* __restrict__ out_w, float* __restrict__ out)
{
    __shared__ float wp[2][NN];     // 4 KB normalized pos weights
    __shared__ float wq[2][NN];     // 4 KB normalized neg weights
    __shared__ float psA[2][2][RD]; // 4 KB m-half partials
    __shared__ float dv[2][RD];     // 2 KB
    const int t = threadIdx.x;
    const int n0 = blockIdx.x << 1;

    if (t < 256){
        #pragma unroll
        for (int j=0;j<2;j++){
            const int n = n0 + j;
            float Sp = 0.f, Sn = 0.f;
            #pragma unroll
            for (int q=0;q<4;q++){
                Sp += Spart[q*NN + n];
                Sn += Spart[(4+q)*NN + n];
            }
            const float ip = 1.0f / Sp, in_ = 1.0f / Sn;
            wp[j][t]     = E_p[n*NN + t] * ip;
            wp[j][t+256] = E_p[n*NN + t + 256] * ip;
            wq[j][t]     = E_n[n*NN + t] * in_;
            wq[j][t+256] = E_n[n*NN + t + 256] * in_;
        }
    }
    __syncthreads();

    {   // phase A: dv[j][c] = sum_m wp[j][m]*r_p[m][c] - wq[j][m]*r_n[m][c]
        const int c = t & 255, mh = t >> 8;
        const int m0 = mh << 8;
        float a0 = 0.f, a1 = 0.f;
        const float* rp = r_p + m0*RD + c;
        const float* rn = r_n + m0*RD + c;
        #pragma unroll 4
        for (int mm=0; mm<256; mm++){
            const int mI = m0 + mm;
            const float vp = *rp; rp += RD;
            const float vn = *rn; rn += RD;
            a0 = fmaf(wp[0][mI], vp, a0); a0 = fmaf(-wq[0][mI], vn, a0);
            a1 = fmaf(wp[1][mI], vp, a1); a1 = fmaf(-wq[1][mI], vn, a1);
        }
        psA[mh][0][c] = a0;
        psA[mh][1][c] = a1;
    }
    __syncthreads();
    if (t < 512){
        const int j = t >> 8, c = t & 255;
        dv[j][c] = psA[0][j][c] + psA[1][j][c];
    }
    __syncthreads();

    {   // phase B: out[j][col] = sum_r dv[j][r]*out_w[r][col], col = t
        float o0 = 0.f, o1 = 0.f;
        const float* wo = out_w + t;
        #pragma unroll 4
        for (int r=0; r<RD; r++){
            const float w = *wo; wo += IN;
            o0 = fmaf(dv[0][r], w, o0);
            o1 = fmaf(dv[1][r], w, o1);
        }
        out[n0*IN + t]     = o0;
        out[(n0+1)*IN + t] = o1;
    }
}

extern "C" void kernel_launch(void* const* d_in, const int* in_sizes, int n_in,
                              void* d_out, int out_size, void* d_ws, size_t ws_size,
                              hipStream_t stream)
{
    const float* fx  = (const float*)d_in[0];
    const float* fp  = (const float*)d_in[1];
    const float* fn  = (const float*)d_in[2];
    const float* gw1 = (const float*)d_in[3];
    const float* gb1 = (const float*)d_in[4];
    const float* gw2 = (const float*)d_in[5];
    const float* gb2 = (const float*)d_in[6];
    const float* ow  = (const float*)d_in[7];
    const float* sw1 = (const float*)d_in[8];
    const float* sb1 = (const float*)d_in[9];
    const float* sw2 = (const float*)d_in[10];
    float* out = (float*)d_out;

    float* ws   = (float*)d_ws;
    float* r_x  = ws;               // 512*256 row-major
    float* r_p  = r_x  + 131072;
    float* r_n  = r_p  + 131072;
    float* rT_p = r_n  + 131072;    // 256*512 column-major
    float* rT_n = rT_p + 131072;
    float* A_x  = rT_n + 131072;    // 512*128 row-major [n][k]
    float* BT_p = A_x  + 65536;     // 128*512 column-major [k][m]
    float* BT_n = BT_p + 65536;
    float* E_p  = BT_n + 65536;     // 512*512
    float* E_n  = E_p  + 262144;
    float* Spar = E_n  + 262144;    // 2*4*512

    hipLaunchKernelGGL(k_rep, dim3(768), dim3(256), 0, stream,
                       fx, fp, fn, gw1, gb1, gw2, gb2, sw1,
                       r_x, r_p, r_n, rT_p, rT_n, A_x, BT_p, BT_n);
    hipLaunchKernelGGL(k_sd, dim3(2048), dim3(256), 0, stream,
                       r_x, rT_p, rT_n, A_x, BT_p, BT_n,
                       sw1, sb1, sw2, E_p, E_n, Spar);
    hipLaunchKernelGGL(k_fin, dim3(256), dim3(512), 0, stream,
                       E_p, E_n, Spar, r_p, r_n, ow, out);
}

// Round 9
// 160.023 us; speedup vs baseline: 1.1472x; 1.1472x over previous
//
#include <hip/hip_runtime.h>
#include <math.h>

#define NN 512   // set size / rows of feat_x
#define IN 512   // INPUT_DIM
#define HD 256   // HIDDEN_DIM
#define RD 256   // REP_DIM
#define SH 128   // SCORE_HIDDEN

// Branchless erf-GELU, Abramowitz-Stegun 7.1.26 (|erf err| <= 1.5e-7).
__device__ __forceinline__ float gelu_fast(float x){
    const float z  = x * 0.70710678118654752f;
    const float az = fabsf(z);
    const float t  = __builtin_amdgcn_rcpf(fmaf(0.3275911f, az, 1.0f));
    float p = fmaf(1.061405429f, t, -1.453152027f);
    p = fmaf(p, t, 1.421413741f);
    p = fmaf(p, t, -0.284496736f);
    p = fmaf(p, t, 0.254829592f);
    p = p * t;
    const float e = __builtin_amdgcn_exp2f(z * z * -1.4426950408889634f);
    const float E = p * e;                        // erfc(|z|)
    const float one_plus_erf = (x >= 0.0f) ? (2.0f - E) : E;
    return 0.5f * x * one_plus_erf;
}

// u*(1+erf(u/sqrt2)) -- the 0.5 is folded into the caller's weight.
__device__ __forceinline__ float gelu2(float u){
    const float az = fabsf(u);
    const float tt = __builtin_amdgcn_rcpf(fmaf(0.23166045f, az, 1.0f));
    float p = fmaf(1.061405429f, tt, -1.453152027f);
    p = fmaf(p, tt, 1.421413741f);
    p = fmaf(p, tt, -0.284496736f);
    p = fmaf(p, tt, 0.254829592f);
    p = p * tt;
    const float e2 = __builtin_amdgcn_exp2f(u * u * -0.72134752044448170f);
    const float Eq = p * e2;                      // erfc(|u|/sqrt2)
    const float ope = (u >= 0.0f) ? (2.0f - Eq) : Eq;
    return u * ope;
}

// K_REP: fused g-MLP + score-net projections. 384 blocks (3 mats x 128
// 4-row groups) x 256 thr. 4 rows/block halves per-CU weight traffic vs
// the 2-row/768-block version (weights are re-streamed per block).
__global__ __launch_bounds__(256) void k_rep(
    const float* __restrict__ fx, const float* __restrict__ fp, const float* __restrict__ fn,
    const float* __restrict__ w1, const float* __restrict__ b1,
    const float* __restrict__ w2, const float* __restrict__ b2,
    const float* __restrict__ s_w1,
    float* __restrict__ r_x, float* __restrict__ r_p, float* __restrict__ r_n,
    float* __restrict__ rT_p, float* __restrict__ rT_n,
    float* __restrict__ A_x, float* __restrict__ BT_p, float* __restrict__ BT_n)
{
    __shared__ float xs[4][IN];        // 8 KB
    __shared__ float ps[4][4][HD];     // 16 KB [slice][row][col]
    __shared__ float hs[4][HD];        // 4 KB
    __shared__ float rloc[4][RD];      // 4 KB
    __shared__ float psf[8][4][SH];    // 16 KB
    __shared__ float ab4[4][SH];       // 2 KB
    const int t = threadIdx.x;
    const int mat = blockIdx.x >> 7;
    const int row0 = (blockIdx.x & 127) << 2;
    const float* src = (mat==0) ? fx : (mat==1) ? fp : fn;

    #pragma unroll
    for (int rep=0; rep<2; rep++){     // stage 4 feat rows: 512 float4s
        const int idx = rep*256 + t;
        const int j = idx >> 7, q = (idx & 127) << 2;
        *(float4*)&xs[j][q] = *(const float4*)&src[(row0+j)*IN + q];
    }
    __syncthreads();

    const int cg = t & 63, s = t >> 6;     // 64 colgroups x 4 K-slices
    const int c0 = cg << 2;

    {   // GEMM1: K=512 in 4 slices of 128
        float4 acc[4];
        #pragma unroll
        for (int j=0;j<4;j++) acc[j] = make_float4(0.f,0.f,0.f,0.f);
        const float* wp = w1 + (s*128)*HD + c0;
        #pragma unroll 8
        for (int ii=0; ii<128; ii++){
            float4 w = *(const float4*)wp; wp += HD;
            const int i = s*128 + ii;
            #pragma unroll
            for (int j=0;j<4;j++){
                const float xv = xs[j][i];
                acc[j].x = fmaf(xv, w.x, acc[j].x);
                acc[j].y = fmaf(xv, w.y, acc[j].y);
                acc[j].z = fmaf(xv, w.z, acc[j].z);
                acc[j].w = fmaf(xv, w.w, acc[j].w);
            }
        }
        #pragma unroll
        for (int j=0;j<4;j++) *(float4*)&ps[s][j][c0] = acc[j];
    }
    __syncthreads();

    #pragma unroll
    for (int rep=0; rep<4; rep++){   // reduce + bias + GELU -> hs
        const int idx = rep*256 + t;
        const int j = idx >> 8, c = idx & 255;
        const float v = b1[c] + ps[0][j][c] + ps[1][j][c] + ps[2][j][c] + ps[3][j][c];
        hs[j][c] = gelu_fast(v);
    }
    __syncthreads();

    {   // GEMM2: K=256 in 4 slices of 64
        float4 acc[4];
        #pragma unroll
        for (int j=0;j<4;j++) acc[j] = make_float4(0.f,0.f,0.f,0.f);
        const float* wp = w2 + (s*64)*RD + c0;
        #pragma unroll 8
        for (int ii=0; ii<64; ii++){
            float4 w = *(const float4*)wp; wp += RD;
            const int i = s*64 + ii;
            #pragma unroll
            for (int j=0;j<4;j++){
                const float xv = hs[j][i];
                acc[j].x = fmaf(xv, w.x, acc[j].x);
                acc[j].y = fmaf(xv, w.y, acc[j].y);
                acc[j].z = fmaf(xv, w.z, acc[j].z);
                acc[j].w = fmaf(xv, w.w, acc[j].w);
            }
        }
        #pragma unroll
        for (int j=0;j<4;j++) *(float4*)&ps[s][j][c0] = acc[j];
    }
    __syncthreads();

    float* rout = (mat==0) ? r_x : (mat==1) ? r_p : r_n;
    #pragma unroll
    for (int rep=0; rep<4; rep++){   // reduce + bias -> rloc + global r
        const int idx = rep*256 + t;
        const int j = idx >> 8, c = idx & 255;
        const float v = b2[c] + ps[0][j][c] + ps[1][j][c] + ps[2][j][c] + ps[3][j][c];
        rloc[j][c] = v;
        rout[(row0+j)*RD + c] = v;
    }
    __syncthreads();

    if (mat){   // transposed rep copy: rT[r][m], float4 across the 4 rows
        float* rT = (mat==1) ? rT_p : rT_n;
        float4 q = make_float4(rloc[0][t], rloc[1][t], rloc[2][t], rloc[3][t]);
        *(float4*)&rT[t*NN + row0] = q;
    }

    {   // score-net projection: 128 cols, K=256 in 8 slices of 32
        const int cg2 = t & 31, s2 = t >> 5;
        const int cc0 = cg2 << 2;
        const float sgn = (mat==0) ? -1.0f : 1.0f;
        const int base1 = (mat==0) ? 0 : 256;
        const float* p1 = s_w1 + (base1 + s2*32)*SH + cc0;
        const float* p3 = s_w1 + (512   + s2*32)*SH + cc0;
        float4 a[4];
        #pragma unroll
        for (int j=0;j<4;j++) a[j] = make_float4(0.f,0.f,0.f,0.f);
        #pragma unroll 8
        for (int ii=0; ii<32; ii++){
            float4 wa = *(const float4*)p1; p1 += SH;
            float4 wd = *(const float4*)p3; p3 += SH;
            float4 w;
            w.x = fmaf(sgn, wd.x, wa.x);
            w.y = fmaf(sgn, wd.y, wa.y);
            w.z = fmaf(sgn, wd.z, wa.z);
            w.w = fmaf(sgn, wd.w, wa.w);
            const int i = s2*32 + ii;
            #pragma unroll
            for (int j=0;j<4;j++){
                const float xv = rloc[j][i];
                a[j].x = fmaf(xv, w.x, a[j].x);
                a[j].y = fmaf(xv, w.y, a[j].y);
                a[j].z = fmaf(xv, w.z, a[j].z);
                a[j].w = fmaf(xv, w.w, a[j].w);
            }
        }
        #pragma unroll
        for (int j=0;j<4;j++) *(float4*)&psf[s2][j][cc0] = a[j];
    }
    __syncthreads();

    #pragma unroll
    for (int rep=0; rep<2; rep++){   // reduce 8 slices: 4 rows x 128 cols
        const int idx = rep*256 + t;
        const int j = idx >> 7, c = idx & 127;
        float v = 0.f;
        #pragma unroll
        for (int ss=0; ss<8; ss++) v += psf[ss][j][c];
        if (mat==0) A_x[(row0+j)*SH + c] = v;
        else        ab4[j][c] = v;
    }
    __syncthreads();
    if (mat && t < 128){   // BT[k][m], float4 across the 4 rows
        float* BT = (mat==1) ? BT_p : BT_n;
        float4 q = make_float4(ab4[0][t], ab4[1][t], ab4[2][t], ab4[3][t]);
        *(float4*)&BT[t*NN + row0] = q;
    }
}

// K_SD: 2048 blocks (set x 256 2-row ntiles x 4 128-m mtiles) x 256 thr
// = 8 blocks/CU = 32 waves/CU. Wave-level k-split, coalesced column-major
// sweeps, conflict-free scalar LDS partials.
__global__ __launch_bounds__(256) void k_sd(
    const float* __restrict__ r_x, const float* __restrict__ rT_p, const float* __restrict__ rT_n,
    const float* __restrict__ A_x, const float* __restrict__ BT_p, const float* __restrict__ BT_n,
    const float* __restrict__ s_w1, const float* __restrict__ s_b1,
    const float* __restrict__ s_w2,
    float* __restrict__ E_p, float* __restrict__ E_n, float* __restrict__ Spart)
{
    __shared__ float2 xs2[RD];        // 2 KB: {x0,x1}[r]
    __shared__ float4 cmb[SH];        // 2 KB: {A0+b1, A1+b1, wn, 0.5*w2}
    __shared__ float pda[2][128];     // stride-4B partials (conflict-free)
    __shared__ float pdb[2][128];
    __shared__ float pdc[2][128];
    __shared__ float nx[2];
    __shared__ float ssum[2][2];      // [m-half][row]
    const int t = threadIdx.x;
    const int set = blockIdx.x >> 10;
    const int rem = blockIdx.x & 1023;
    const int n0 = (rem >> 2) << 1;
    const int mt = rem & 3;
    const int mbase = mt << 7;
    const int tm = t & 127, kh = t >> 7;   // kh uniform per wave
    const int m = mbase + tm;
    const float* yT = set ? rT_n : rT_p;
    const float* BT = set ? BT_n : BT_p;
    float* E = set ? E_n : E_p;

    xs2[t] = make_float2(r_x[n0*RD + t], r_x[(n0+1)*RD + t]);
    if (t < SH){
        const float b1v = s_b1[t];
        cmb[t] = make_float4(A_x[n0*SH + t] + b1v,
                             A_x[(n0+1)*SH + t] + b1v,
                             s_w1[768*SH + t],
                             0.5f * s_w2[t]);
    }
    __syncthreads();

    // x-row norms (waves 0,1 -> rows 0,1)
    if (t < 128){
        const int w = t >> 6, l = t & 63;
        float v = 0.f;
        #pragma unroll
        for (int q=0;q<4;q++){
            const float2 e = xs2[l + 64*q];
            const float ev = w ? e.y : e.x;
            v = fmaf(ev, ev, v);
        }
        #pragma unroll
        for (int off=32; off>=1; off>>=1) v += __shfl_xor(v, off);
        if (l==0) nx[w] = v;
    }

    // phase 1: dots + ||y||^2 over this wave's r-half (coalesced loads)
    float d0=0.f, d1=0.f, ny=0.f;
    {
        const float* yp = yT + (kh << 7)*NN + m;
        #pragma unroll 16
        for (int rr=0; rr<128; rr++){
            const float y = yp[rr*NN];
            const float2 xv = xs2[(kh << 7) + rr];
            d0 = fmaf(xv.x, y, d0);
            d1 = fmaf(xv.y, y, d1);
            ny = fmaf(y, y, ny);
        }
    }
    pda[kh][tm] = d0; pdb[kh][tm] = d1; pdc[kh][tm] = ny;
    __syncthreads();
    d0 += pda[1-kh][tm]; d1 += pdb[1-kh][tm]; ny += pdc[1-kh][tm];
    const float dn0 = sqrtf(fmaxf(fmaf(-2.f, d0, nx[0] + ny), 0.f));
    const float dn1 = sqrtf(fmaxf(fmaf(-2.f, d1, nx[1] + ny), 0.f));

    // phase 2: logits over this wave's k-half (coalesced BT loads)
    float acc0 = 0.f, acc1 = 0.f;
    {
        const float* bp = BT + (kh << 6)*NN + m;
        #pragma unroll 4
        for (int kk=0; kk<64; kk++){
            const float b = bp[kk*NN];
            const float4 c = cmb[(kh << 6) + kk];
            const float u0 = fmaf(dn0, c.z, c.x + b);
            const float u1 = fmaf(dn1, c.z, c.y + b);
            acc0 = fmaf(c.w, gelu2(u0), acc0);
            acc1 = fmaf(c.w, gelu2(u1), acc1);
        }
    }
    __syncthreads();                       // partner done reading phase-1 pd
    pda[kh][tm] = acc0; pdb[kh][tm] = acc1;
    __syncthreads();
    if (kh == 0){
        // s_b2 omitted (softmax shift-invariant); no max pass (logits O(1))
        const float ev0 = __builtin_amdgcn_exp2f((acc0 + pda[1][tm]) * 1.4426950408889634f);
        const float ev1 = __builtin_amdgcn_exp2f((acc1 + pdb[1][tm]) * 1.4426950408889634f);
        E[n0*NN + m]     = ev0;
        E[(n0+1)*NN + m] = ev1;
        float v0 = ev0, v1 = ev1;
        #pragma unroll
        for (int off=32; off>=1; off>>=1){ v0 += __shfl_xor(v0, off); v1 += __shfl_xor(v1, off); }
        if ((t & 63) == 0){
            ssum[tm >> 6][0] = v0;
            ssum[tm >> 6][1] = v1;
        }
    }
    __syncthreads();
    if (t < 2)
        Spart[(set*4 + mt)*NN + n0 + t] = ssum[0][t] + ssum[1][t];
}

// K_FIN: normalize + einsum + out-projection. 256 blocks x 1024 thr
// (16 waves/CU). Phase A: 16 m-slices (8 pos + 8 neg) x 64 float4-colgroups;
// LDS reduce; phase B: 2 rows x 512 cols, one output/thread.
__global__ __launch_bounds__(1024) void k_fin(
    const float* __restrict__ E_p, const float* __restrict__ E_n,
    const float* __restrict__ Spart,
    const float* __restrict__ r_p, const float* __restrict__ r_n,
    const float* __restrict__ out_w, float* __restrict__ out)
{
    __shared__ float wgt[2][2][NN];   // 8 KB [set][row][m] normalized weights
    __shared__ float psA[16][2][RD];  // 32 KB
    __shared__ float dv[2][RD];       // 2 KB
    __shared__ float sinv[4];
    const int t = threadIdx.x;
    const int n0 = blockIdx.x << 1;

    if (t < 4){
        const int se = t >> 1, j = t & 1;
        float S = 0.f;
        #pragma unroll
        for (int q=0;q<4;q++) S += Spart[(se*4+q)*NN + n0 + j];
        sinv[t] = 1.0f / S;
    }
    __syncthreads();
    #pragma unroll
    for (int rep=0; rep<2; rep++){    // se = rep; coalesced E loads
        const int idx = (rep << 10) + t;
        const int j = (idx >> 9) & 1, m = idx & 511;
        const float* E = rep ? E_n : E_p;
        wgt[rep][j][m] = E[(n0+j)*NN + m] * sinv[rep*2 + j];
    }
    __syncthreads();

    {   // phase A: partial dv over this slice's 64 m (float4 r loads)
        const int cg = t & 63, sl = t >> 6;
        const int c0 = cg << 2;
        const int se = sl >> 3;
        const int m0 = (sl & 7) << 6;
        const float* rsrc = se ? r_n : r_p;
        float4 a0 = make_float4(0.f,0.f,0.f,0.f), a1 = a0;
        const float* rp = rsrc + m0*RD + c0;
        #pragma unroll 8
        for (int mm=0; mm<64; mm++){
            const float4 rv = *(const float4*)rp; rp += RD;
            const float w0 = wgt[se][0][m0+mm];
            const float w1v = wgt[se][1][m0+mm];
            a0.x = fmaf(w0, rv.x, a0.x); a0.y = fmaf(w0, rv.y, a0.y);
            a0.z = fmaf(w0, rv.z, a0.z); a0.w = fmaf(w0, rv.w, a0.w);
            a1.x = fmaf(w1v, rv.x, a1.x); a1.y = fmaf(w1v, rv.y, a1.y);
            a1.z = fmaf(w1v, rv.z, a1.z); a1.w = fmaf(w1v, rv.w, a1.w);
        }
        *(float4*)&psA[sl][0][c0] = a0;
        *(float4*)&psA[sl][1][c0] = a1;
    }
    __syncthreads();
    if (t < 512){   // dv = (pos partials) - (neg partials)
        const int j = t >> 8, c = t & 255;
        float v = 0.f;
        #pragma unroll
        for (int ss=0; ss<8; ss++)  v += psA[ss][j][c];
        #pragma unroll
        for (int ss=8; ss<16; ss++) v -= psA[ss][j][c];
        dv[j][c] = v;
    }
    __syncthreads();

    {   // phase B: out[j][col] = sum_r dv[j][r]*out_w[r][col]
        const int col = t & 511, j = t >> 9;
        float o = 0.f;
        const float* wo = out_w + col;
        #pragma unroll 8
        for (int r=0; r<RD; r++){ o = fmaf(dv[j][r], *wo, o); wo += IN; }
        out[(n0+j)*IN + col] = o;
    }
}

extern "C" void kernel_launch(void* const* d_in, const int* in_sizes, int n_in,
                              void* d_out, int out_size, void* d_ws, size_t ws_size,
                              hipStream_t stream)
{
    const float* fx  = (const float*)d_in[0];
    const float* fp  = (const float*)d_in[1];
    const float* fn  = (const float*)d_in[2];
    const float* gw1 = (const float*)d_in[3];
    const float* gb1 = (const float*)d_in[4];
    const float* gw2 = (const float*)d_in[5];
    const float* gb2 = (const float*)d_in[6];
    const float* ow  = (const float*)d_in[7];
    const float* sw1 = (const float*)d_in[8];
    const float* sb1 = (const float*)d_in[9];
    const float* sw2 = (const float*)d_in[10];
    float* out = (float*)d_out;

    float* ws   = (float*)d_ws;
    float* r_x  = ws;               // 512*256 row-major
    float* r_p  = r_x  + 131072;
    float* r_n  = r_p  + 131072;
    float* rT_p = r_n  + 131072;    // 256*512 column-major
    float* rT_n = rT_p + 131072;
    float* A_x  = rT_n + 131072;    // 512*128 row-major [n][k]
    float* BT_p = A_x  + 65536;     // 128*512 column-major [k][m]
    float* BT_n = BT_p + 65536;
    float* E_p  = BT_n + 65536;     // 512*512
    float* E_n  = E_p  + 262144;
    float* Spar = E_n  + 262144;    // 2*4*512

    hipLaunchKernelGGL(k_rep, dim3(384), dim3(256), 0, stream,
                       fx, fp, fn, gw1, gb1, gw2, gb2, sw1,
                       r_x, r_p, r_n, rT_p, rT_n, A_x, BT_p, BT_n);
    hipLaunchKernelGGL(k_sd, dim3(2048), dim3(256), 0, stream,
                       r_x, rT_p, rT_n, A_x, BT_p, BT_n,
                       sw1, sb1, sw2, E_p, E_n, Spar);
    hipLaunchKernelGGL(k_fin, dim3(256), dim3(1024), 0, stream,
                       E_p, E_n, Spar, r_p, r_n, ow, out);
}